// Round 7
// baseline (65.340 us; speedup 1.0000x reference)
//
#include <hip/hip_runtime.h>

#define DHW  8192
#define COFF 108

typedef __attribute__((ext_vector_type(8))) short bf16x8;
typedef __attribute__((ext_vector_type(4))) float f32x4;
typedef __bf16 bfv2 __attribute__((ext_vector_type(2)));

__device__ inline unsigned short f2bf(float f) {
    unsigned u = __float_as_uint(f);
    u += 0x7fffu + ((u >> 16) & 1u);     // RNE
    return (unsigned short)(u >> 16);
}
__device__ inline float bf2f(unsigned short h) {
    return __uint_as_float(((unsigned)h) << 16);
}

// dot2: c += a.lo*b.lo + a.hi*b.hi  (bf16 pairs packed in dwords)
__device__ inline float dot2bf(unsigned a, unsigned b, float c) {
#if defined(__has_builtin) && __has_builtin(__builtin_amdgcn_fdot2_f32_bf16)
    return __builtin_amdgcn_fdot2_f32_bf16(__builtin_bit_cast(bfv2, a),
                                           __builtin_bit_cast(bfv2, b), c, false);
#else
    c += __uint_as_float(a << 16) * __uint_as_float(b << 16);
    c += __uint_as_float(a & 0xffff0000u) * __uint_as_float(b & 0xffff0000u);
    return c;
#endif
}

// ---------------- kernel A: xt transpose + weight packing -------------------
__global__ __launch_bounds__(256) void k_prep(
    const float* __restrict__ x, const float* __restrict__ w_off,
    const float* __restrict__ w_dcn,
    ushort* __restrict__ xt, ushort* __restrict__ pA1,
    ushort* __restrict__ pAc, ushort* __restrict__ pW)
{
    __shared__ ushort tile[16 * 66];
    const int bi = blockIdx.x;
    const int tid = threadIdx.x;
    if (bi < 1024) {
        const int b  = bi >> 9;
        const int f0 = (bi & 511) * 16;
        #pragma unroll
        for (int it = 0; it < 4; ++it) {
            int c = it * 16 + (tid >> 4), f = tid & 15;
            tile[f * 66 + c] = f2bf(x[((size_t)(b * 64 + c)) * DHW + f0 + f]);
        }
        __syncthreads();
        #pragma unroll
        for (int it = 0; it < 4; ++it) {
            int f = it * 4 + (tid >> 6), c = tid & 63;
            xt[((size_t)b * DHW + f0 + f) * 64 + c] = tile[f * 66 + c];
        }
    } else {
        int t0 = (bi - 1024) * 256 + tid;
        const int stride = 32 * 256;
        for (int i = t0; i < 27 * 2 * 7 * 512; i += stride) {
            int j = i & 7, l = (i >> 3) & 63, rest = i >> 9;
            int m = rest % 7, ch = (rest / 7) & 1, tap = rest / 14;
            int co = m * 16 + (l & 15);
            int ci = ch * 32 + (l >> 4) * 8 + j;
            pA1[i] = (co < COFF) ? f2bf(w_off[(co * 67 + ci) * 27 + tap]) : (ushort)0;
        }
        for (int i = t0; i < 3 * 7 * 512; i += stride) {
            int j = i & 7, l = (i >> 3) & 63, rest = i >> 9;
            int m = rest % 7, t = rest / 7;
            int co = m * 16 + (l & 15);
            int flatk = t * 32 + (l >> 4) * 8 + j;
            ushort v = 0;
            if (co < COFF && flatk < 81) {
                int cc = flatk / 27, tap = flatk % 27;
                v = f2bf(w_off[(co * 67 + 64 + cc) * 27 + tap]);
            }
            pAc[i] = v;
        }
        for (int i = t0; i < 27 * 2 * 4 * 512; i += stride) {
            int j = i & 7, l = (i >> 3) & 63;
            int m = (i >> 9) & 3, ch = (i >> 11) & 1, k = i >> 12;
            int o = m * 16 + (l & 15);
            int c = ch * 32 + (l >> 4) * 8 + j;
            pW[i] = f2bf(w_dcn[(o * 64 + c) * 27 + k]);
        }
    }
}

// ---------------- kernel B: fused conv -> corners -> sample+GEMM ------------
// 512 threads (8 waves), 32 sp (full h-row), grid 512 = 2 blocks/CU
__global__ __launch_bounds__(512, 4) void k_fused(
    const ushort* __restrict__ xt, const ushort* __restrict__ pA1,
    const ushort* __restrict__ pAc, const ushort* __restrict__ pW,
    const float* __restrict__ b_off, const float* __restrict__ b_dcn,
    float* __restrict__ out)
{
    __shared__ __align__(16) char smem[64768];
    ushort* pred_lds = (ushort*)smem;           // 6912 B  bf16 [108][32]
    char*   region   = smem + 6912;             // 57856 B union:
    //  stage-1: red1 uint2[(sw*14+i)*64+lane]          (57344 B)
    //  stage-2: cwi uint4[(k*2+half)*32+p]   @0        (27648 B)
    //           cww uint4[k*32+p]            @27648    (13824 B)
    //           S  [str][buf][32p][128B]     @41472    (16384 B)
    //           red2 f32x4[(m4*2+pt)*64+l]   @41472    ( 8192 B, after S dead)

    const int bi   = blockIdx.x;
    const int b    = bi >> 8;
    const int sp32 = bi & 255;
    const int d    = sp32 >> 5;
    const int h    = sp32 & 31;
    const int spg  = sp32 * 32;
    const int tid  = threadIdx.x;
    const int wv = tid >> 6, lane = tid & 63, q = lane >> 4, r16 = lane & 15;
    const ushort* __restrict__ xb = xt + (size_t)b * DHW * 64;

    // ===== stage 1: offset conv, 8-way K-split, pt-in-wave (N=32) =====
    f32x4 acc1[14] = {};      // [m*2 + pt]
    for (int c = wv; c < 57; c += 8) {
        bf16x8 bf[2];
        const ushort* pa;
        if (c < 54) {
            int tap = c >> 1, ch = c & 1;
            int dz = tap / 9, rem9 = tap - dz * 9, dy = rem9 / 3, dx = rem9 - dy * 3;
            int zz = d + dz - 1, yy = h + dy - 1;
            int basepos = (zz << 10) + (yy << 5);
            bool okzy = ((unsigned)zz < 8u) & ((unsigned)yy < 32u);
            #pragma unroll
            for (int pt = 0; pt < 2; ++pt) {
                int xx = pt * 16 + r16 + dx - 1;
                bool ok = okzy & ((unsigned)xx < 32u);
                bf16x8 tv = {};
                if (ok) tv = *(const bf16x8*)(xb + (size_t)(basepos + xx) * 64
                                              + ch * 32 + q * 8);
                bf[pt] = tv;
            }
            pa = pA1 + (size_t)((tap * 2 + ch) * 7) * 512 + lane * 8;
        } else {
            int t = c - 54;
            #pragma unroll
            for (int pt = 0; pt < 2; ++pt) {
                bf16x8 bt;
                #pragma unroll
                for (int j = 0; j < 8; ++j) {
                    int flatk = t * 32 + q * 8 + j;
                    int cc = flatk / 27, tap = flatk % 27;
                    int dz = tap / 9, rem9 = tap - dz * 9, dy = rem9 / 3, dx = rem9 - dy * 3;
                    int zz = d + dz - 1, yy = h + dy - 1, xx = pt * 16 + r16 + dx - 1;
                    bool ok = (flatk < 81) & ((unsigned)zz < 8u) & ((unsigned)yy < 32u)
                              & ((unsigned)xx < 32u);
                    float val = 0.f;
                    if (ok)
                        val = (cc == 0) ? (-1.f + (2.f / 7.f) * (float)zz)
                            : (cc == 1) ? (-1.f + (2.f / 31.f) * (float)yy)
                                        : (-1.f + (2.f / 31.f) * (float)xx);
                    bt[j] = (short)f2bf(val);
                }
                bf[pt] = bt;
            }
            pa = pAc + (size_t)(t * 7) * 512 + lane * 8;
        }
        #pragma unroll
        for (int m = 0; m < 7; ++m) {
            bf16x8 af = *(const bf16x8*)(pa + m * 512);
            acc1[m * 2 + 0] = __builtin_amdgcn_mfma_f32_16x16x32_bf16(af, bf[0], acc1[m * 2 + 0], 0, 0, 0);
            acc1[m * 2 + 1] = __builtin_amdgcn_mfma_f32_16x16x32_bf16(af, bf[1], acc1[m * 2 + 1], 0, 0, 0);
        }
    }
    // distributed bf16-partial reduce across the 8 waves
    {
        uint2* red1 = (uint2*)region;
        #pragma unroll
        for (int i = 0; i < 14; ++i) {
            f32x4 s = acc1[i];
            uint2 pk2;
            pk2.x = (unsigned)f2bf(s[0]) | ((unsigned)f2bf(s[1]) << 16);
            pk2.y = (unsigned)f2bf(s[2]) | ((unsigned)f2bf(s[3]) << 16);
            red1[(wv * 14 + i) * 64 + lane] = pk2;
        }
        __syncthreads();
        for (int i = wv; i < 14; i += 8) {
            float s0 = 0.f, s1 = 0.f, s2 = 0.f, s3 = 0.f;
            #pragma unroll
            for (int sw = 0; sw < 8; ++sw) {
                uint2 v = red1[(sw * 14 + i) * 64 + lane];
                s0 += bf2f((unsigned short)(v.x & 0xffffu));
                s1 += bf2f((unsigned short)(v.x >> 16));
                s2 += bf2f((unsigned short)(v.y & 0xffffu));
                s3 += bf2f((unsigned short)(v.y >> 16));
            }
            int m = i >> 1, pt = i & 1;
            float sr[4] = {s0, s1, s2, s3};
            #pragma unroll
            for (int r = 0; r < 4; ++r) {
                int co = m * 16 + q * 4 + r;
                if (co < COFF)
                    pred_lds[co * 32 + pt * 16 + r16] = f2bf(sr[r] + b_off[co]);
            }
        }
        __syncthreads();
    }

    // ===== corner tables (32 p) =====
    uint4* cwi = (uint4*)region;
    uint4* cww = (uint4*)(region + 27648);
    for (int kp = tid; kp < 27 * 32; kp += 512) {
        int k = kp >> 5, p = kp & 31;
        float offz = bf2f(pred_lds[(k * 3 + 0) * 32 + p]);
        float offy = bf2f(pred_lds[(k * 3 + 1) * 32 + p]);
        float offx = bf2f(pred_lds[(k * 3 + 2) * 32 + p]);
        float av   = bf2f(pred_lds[(81 + k) * 32 + p]);
        float alpha = 1.f / (1.f + __expf(-av));
        int kz = k / 9, rem = k - kz * 9, ky = rem / 3, kx = rem - ky * 3;
        float pz = (float)(d + kz - 1) + offz;
        float py = (float)(h + ky - 1) + offy;
        float px = (float)(p + kx - 1) + offx;
        float fz = floorf(pz), fy = floorf(py), fx = floorf(px);
        float tz = pz - fz, ty = py - fy, tx = px - fx;
        int iz0 = (int)fz, iy0 = (int)fy, ix0 = (int)fx;
        unsigned idxs[8]; float wgts[8];
        #pragma unroll
        for (int c8 = 0; c8 < 8; ++c8) {
            int czi = c8 >> 2, cyi = (c8 >> 1) & 1, cxi = c8 & 1;
            int iz = iz0 + czi, iy = iy0 + cyi, ix = ix0 + cxi;
            float wz = czi ? tz : 1.f - tz;
            float wy = cyi ? ty : 1.f - ty;
            float wx = cxi ? tx : 1.f - tx;
            bool ok = ((unsigned)iz < 8u) && ((unsigned)iy < 32u) && ((unsigned)ix < 32u);
            idxs[c8] = ok ? ((unsigned)((iz << 10) + (iy << 5) + ix) << 7) : 0u;
            wgts[c8] = ok ? wz * wy * wx * alpha : 0.f;
        }
        cwi[(k * 2 + 0) * 32 + p] = make_uint4(idxs[0], idxs[1], idxs[2], idxs[3]);
        cwi[(k * 2 + 1) * 32 + p] = make_uint4(idxs[4], idxs[5], idxs[6], idxs[7]);
        cww[k * 32 + p] = make_uint4(
            (unsigned)f2bf(wgts[0]) | ((unsigned)f2bf(wgts[1]) << 16),
            (unsigned)f2bf(wgts[2]) | ((unsigned)f2bf(wgts[3]) << 16),
            (unsigned)f2bf(wgts[4]) | ((unsigned)f2bf(wgts[5]) << 16),
            (unsigned)f2bf(wgts[6]) | ((unsigned)f2bf(wgts[7]) << 16));
    }
    __syncthreads();

    // ===== stage 2: sample (full lines) + GEMM, pt-in-wave (N=32) =====
    // sampling role: str = wv>>2 (k parity), pq = wv&3 (position octet)
    // MFMA role:     ch  = wv>>2 (c half),   m4 = wv&3 (o tile)
    char* Sbuf = region + 41472;
    const int str = wv >> 2, pq = wv & 3;
    const int pr = lane >> 3, cg = lane & 7;
    const int p2 = pq * 8 + pr;
    const int m4 = wv & 3, ch = wv >> 2;
    const char* xbB = (const char*)xb + cg * 16;
    const unsigned swz_w = (unsigned)(str * 8192 + p2 * 128 + ((cg * 16) ^ ((p2 & 7) << 4)));
    unsigned swz_r[2];
    #pragma unroll
    for (int pt = 0; pt < 2; ++pt) {
        int p = pt * 16 + r16;
        swz_r[pt] = (unsigned)(p * 128 + ((ch * 64 + q * 16) ^ ((p & 7) << 4)));
    }

    f32x4 acc2[2] = {};
    for (int t = 0; t < 14; ++t) {
        const int ks0 = 2 * t + str;
        if (ks0 < 27) {
            uint4 wq = cww[ks0 * 32 + p2];
            uint4 i0 = cwi[(ks0 * 2 + 0) * 32 + p2];
            uint4 i1 = cwi[(ks0 * 2 + 1) * 32 + p2];
            unsigned iv[8] = {i0.x, i0.y, i0.z, i0.w, i1.x, i1.y, i1.z, i1.w};
            uint4 xv[8];
            #pragma unroll
            for (int c8 = 0; c8 < 8; ++c8)
                xv[c8] = *(const uint4*)(xbB + iv[c8]);
            unsigned wp[4] = {wq.x, wq.y, wq.z, wq.w};
            float sa[8] = {};
            #pragma unroll
            for (int cp = 0; cp < 4; ++cp) {
                unsigned ua[4] = {xv[cp * 2 + 0].x, xv[cp * 2 + 0].y, xv[cp * 2 + 0].z, xv[cp * 2 + 0].w};
                unsigned ub[4] = {xv[cp * 2 + 1].x, xv[cp * 2 + 1].y, xv[cp * 2 + 1].z, xv[cp * 2 + 1].w};
                #pragma unroll
                for (int dw = 0; dw < 4; ++dw) {
                    unsigned plo = __builtin_amdgcn_perm(ub[dw], ua[dw], 0x05040100u);
                    unsigned phi = __builtin_amdgcn_perm(ub[dw], ua[dw], 0x07060302u);
                    sa[dw * 2 + 0] = dot2bf(plo, wp[cp], sa[dw * 2 + 0]);
                    sa[dw * 2 + 1] = dot2bf(phi, wp[cp], sa[dw * 2 + 1]);
                }
            }
            uint4 pk;
            pk.x = (unsigned)f2bf(sa[0]) | ((unsigned)f2bf(sa[1]) << 16);
            pk.y = (unsigned)f2bf(sa[2]) | ((unsigned)f2bf(sa[3]) << 16);
            pk.z = (unsigned)f2bf(sa[4]) | ((unsigned)f2bf(sa[5]) << 16);
            pk.w = (unsigned)f2bf(sa[6]) | ((unsigned)f2bf(sa[7]) << 16);
            *(uint4*)(Sbuf + (t & 1) * 4096 + swz_w) = pk;
        }
        __syncthreads();
        #pragma unroll
        for (int ks = 0; ks < 2; ++ks) {
            int k = 2 * t + ks;
            if (k < 27) {
                bf16x8 af = *(const bf16x8*)(pW + (size_t)((k * 2 + ch) * 4 + m4) * 512 + lane * 8);
                #pragma unroll
                for (int pt = 0; pt < 2; ++pt) {
                    bf16x8 bv = *(const bf16x8*)(Sbuf + ks * 8192 + (t & 1) * 4096 + swz_r[pt]);
                    acc2[pt] = __builtin_amdgcn_mfma_f32_16x16x32_bf16(af, bv, acc2[pt], 0, 0, 0);
                }
            }
        }
    }

    __syncthreads();
    f32x4* red2 = (f32x4*)(region + 41472);
    if (wv >= 4) {
        red2[(m4 * 2 + 0) * 64 + lane] = acc2[0];
        red2[(m4 * 2 + 1) * 64 + lane] = acc2[1];
    }
    __syncthreads();
    if (wv < 4) {
        float* __restrict__ outb = out + (size_t)b * 64 * DHW + spg;
        #pragma unroll
        for (int pt = 0; pt < 2; ++pt) {
            f32x4 s = acc2[pt] + red2[(m4 * 2 + pt) * 64 + lane];
            #pragma unroll
            for (int r = 0; r < 4; ++r) {
                int o = m4 * 16 + q * 4 + r;
                outb[(size_t)o * DHW + pt * 16 + r16] = s[r] + b_dcn[o];
            }
        }
    }
}

extern "C" void kernel_launch(void* const* d_in, const int* in_sizes, int n_in,
                              void* d_out, int out_size, void* d_ws, size_t ws_size,
                              hipStream_t stream) {
    const float* x     = (const float*)d_in[0];
    const float* w_off = (const float*)d_in[1];
    const float* b_off = (const float*)d_in[2];
    const float* w_dcn = (const float*)d_in[3];
    const float* b_dcn = (const float*)d_in[4];
    float* out = (float*)d_out;

    ushort* xt  = (ushort*)d_ws;                          // 2,097,152 B
    ushort* pA1 = (ushort*)((char*)d_ws + 2097152);       //   387,072 B
    ushort* pAc = (ushort*)((char*)d_ws + 2484224);       //    21,504 B
    ushort* pW  = (ushort*)((char*)d_ws + 2505728);       //   221,184 B

    k_prep <<<1056, 256, 0, stream>>>(x, w_off, w_dcn, xt, pA1, pAc, pW);
    k_fused<<<512, 512, 0, stream>>>(xt, pA1, pAc, pW, b_off, b_dcn, out);
}

// Round 8
// 64.421 us; speedup vs baseline: 1.0143x; 1.0143x over previous
//
#include <hip/hip_runtime.h>

#define DHW  8192
#define COFF 108

typedef __attribute__((ext_vector_type(8))) short bf16x8;
typedef __attribute__((ext_vector_type(4))) float f32x4;
typedef __bf16 bfv2 __attribute__((ext_vector_type(2)));

__device__ inline unsigned short f2bf(float f) {
    unsigned u = __float_as_uint(f);
    u += 0x7fffu + ((u >> 16) & 1u);     // RNE
    return (unsigned short)(u >> 16);
}
__device__ inline float bf2f(unsigned short h) {
    return __uint_as_float(((unsigned)h) << 16);
}

// dot2: c += a.lo*b.lo + a.hi*b.hi  (bf16 pairs packed in dwords)
__device__ inline float dot2bf(unsigned a, unsigned b, float c) {
#if defined(__has_builtin) && __has_builtin(__builtin_amdgcn_fdot2_f32_bf16)
    return __builtin_amdgcn_fdot2_f32_bf16(__builtin_bit_cast(bfv2, a),
                                           __builtin_bit_cast(bfv2, b), c, false);
#else
    c += __uint_as_float(a << 16) * __uint_as_float(b << 16);
    c += __uint_as_float(a & 0xffff0000u) * __uint_as_float(b & 0xffff0000u);
    return c;
#endif
}

// ---------------- kernel A: xt transpose + weight packing -------------------
__global__ __launch_bounds__(256) void k_prep(
    const float* __restrict__ x, const float* __restrict__ w_off,
    const float* __restrict__ w_dcn,
    ushort* __restrict__ xt, ushort* __restrict__ pA1,
    ushort* __restrict__ pAc, ushort* __restrict__ pW)
{
    __shared__ ushort tile[16 * 66];
    const int bi = blockIdx.x;
    const int tid = threadIdx.x;
    if (bi < 1024) {
        const int b  = bi >> 9;
        const int f0 = (bi & 511) * 16;
        #pragma unroll
        for (int it = 0; it < 4; ++it) {
            int c = it * 16 + (tid >> 4), f = tid & 15;
            tile[f * 66 + c] = f2bf(x[((size_t)(b * 64 + c)) * DHW + f0 + f]);
        }
        __syncthreads();
        #pragma unroll
        for (int it = 0; it < 4; ++it) {
            int f = it * 4 + (tid >> 6), c = tid & 63;
            xt[((size_t)b * DHW + f0 + f) * 64 + c] = tile[f * 66 + c];
        }
    } else {
        int t0 = (bi - 1024) * 256 + tid;
        const int stride = 32 * 256;
        for (int i = t0; i < 27 * 2 * 7 * 512; i += stride) {
            int j = i & 7, l = (i >> 3) & 63, rest = i >> 9;
            int m = rest % 7, ch = (rest / 7) & 1, tap = rest / 14;
            int co = m * 16 + (l & 15);
            int ci = ch * 32 + (l >> 4) * 8 + j;
            pA1[i] = (co < COFF) ? f2bf(w_off[(co * 67 + ci) * 27 + tap]) : (ushort)0;
        }
        for (int i = t0; i < 3 * 7 * 512; i += stride) {
            int j = i & 7, l = (i >> 3) & 63, rest = i >> 9;
            int m = rest % 7, t = rest / 7;
            int co = m * 16 + (l & 15);
            int flatk = t * 32 + (l >> 4) * 8 + j;
            ushort v = 0;
            if (co < COFF && flatk < 81) {
                int cc = flatk / 27, tap = flatk % 27;
                v = f2bf(w_off[(co * 67 + 64 + cc) * 27 + tap]);
            }
            pAc[i] = v;
        }
        for (int i = t0; i < 27 * 2 * 4 * 512; i += stride) {
            int j = i & 7, l = (i >> 3) & 63;
            int m = (i >> 9) & 3, ch = (i >> 11) & 1, k = i >> 12;
            int o = m * 16 + (l & 15);
            int c = ch * 32 + (l >> 4) * 8 + j;
            pW[i] = f2bf(w_dcn[(o * 64 + c) * 27 + k]);
        }
    }
}

// ---------------- kernel B: fused conv -> corners -> sample+GEMM ------------
// 512 threads (8 waves), 32 sp (full h-row), grid 512 = 2 blocks/CU
// stage-2 is barrier-free: wave=(pt,ch,kh), in-wave bpermute transpose
__global__ __launch_bounds__(512, 4) void k_fused(
    const ushort* __restrict__ xt, const ushort* __restrict__ pA1,
    const ushort* __restrict__ pAc, const ushort* __restrict__ pW,
    const float* __restrict__ b_off, const float* __restrict__ b_dcn,
    float* __restrict__ out)
{
    __shared__ __align__(16) char smem[64256];
    ushort* pred_lds = (ushort*)smem;           // 6912 B  bf16 [108][32]
    char*   region   = smem + 6912;             // 57344 B union:
    //  stage-1: red1 uint2[(sw*14+i)*64+lane]          (57344 B)
    //  stage-2: cwi uint4[(k*2+half)*32+p]   @0        (27648 B)
    //           cww uint4[k*32+p]            @27648    (13824 B)
    //  epilog:  red2 f32x4[(wv*4+m)*64+l]    @0        (32768 B, after cwi dead)

    const int bi   = blockIdx.x;
    const int b    = bi >> 8;
    const int sp32 = bi & 255;
    const int d    = sp32 >> 5;
    const int h    = sp32 & 31;
    const int spg  = sp32 * 32;
    const int tid  = threadIdx.x;
    const int wv = tid >> 6, lane = tid & 63, q = lane >> 4, r16 = lane & 15;
    const ushort* __restrict__ xb = xt + (size_t)b * DHW * 64;

    // ===== stage 1: offset conv, 8-way K-split, pt-in-wave (N=32) =====
    f32x4 acc1[14] = {};      // [m*2 + pt]
    for (int c = wv; c < 57; c += 8) {
        bf16x8 bf[2];
        const ushort* pa;
        if (c < 54) {
            int tap = c >> 1, ch = c & 1;
            int dz = tap / 9, rem9 = tap - dz * 9, dy = rem9 / 3, dx = rem9 - dy * 3;
            int zz = d + dz - 1, yy = h + dy - 1;
            int basepos = (zz << 10) + (yy << 5);
            bool okzy = ((unsigned)zz < 8u) & ((unsigned)yy < 32u);
            #pragma unroll
            for (int pt = 0; pt < 2; ++pt) {
                int xx = pt * 16 + r16 + dx - 1;
                bool ok = okzy & ((unsigned)xx < 32u);
                bf16x8 tv = {};
                if (ok) tv = *(const bf16x8*)(xb + (size_t)(basepos + xx) * 64
                                              + ch * 32 + q * 8);
                bf[pt] = tv;
            }
            pa = pA1 + (size_t)((tap * 2 + ch) * 7) * 512 + lane * 8;
        } else {
            int t = c - 54;
            #pragma unroll
            for (int pt = 0; pt < 2; ++pt) {
                bf16x8 bt;
                #pragma unroll
                for (int j = 0; j < 8; ++j) {
                    int flatk = t * 32 + q * 8 + j;
                    int cc = flatk / 27, tap = flatk % 27;
                    int dz = tap / 9, rem9 = tap - dz * 9, dy = rem9 / 3, dx = rem9 - dy * 3;
                    int zz = d + dz - 1, yy = h + dy - 1, xx = pt * 16 + r16 + dx - 1;
                    bool ok = (flatk < 81) & ((unsigned)zz < 8u) & ((unsigned)yy < 32u)
                              & ((unsigned)xx < 32u);
                    float val = 0.f;
                    if (ok)
                        val = (cc == 0) ? (-1.f + (2.f / 7.f) * (float)zz)
                            : (cc == 1) ? (-1.f + (2.f / 31.f) * (float)yy)
                                        : (-1.f + (2.f / 31.f) * (float)xx);
                    bt[j] = (short)f2bf(val);
                }
                bf[pt] = bt;
            }
            pa = pAc + (size_t)(t * 7) * 512 + lane * 8;
        }
        #pragma unroll
        for (int m = 0; m < 7; ++m) {
            bf16x8 af = *(const bf16x8*)(pa + m * 512);
            acc1[m * 2 + 0] = __builtin_amdgcn_mfma_f32_16x16x32_bf16(af, bf[0], acc1[m * 2 + 0], 0, 0, 0);
            acc1[m * 2 + 1] = __builtin_amdgcn_mfma_f32_16x16x32_bf16(af, bf[1], acc1[m * 2 + 1], 0, 0, 0);
        }
    }
    // distributed bf16-partial reduce across the 8 waves
    {
        uint2* red1 = (uint2*)region;
        #pragma unroll
        for (int i = 0; i < 14; ++i) {
            f32x4 s = acc1[i];
            uint2 pk2;
            pk2.x = (unsigned)f2bf(s[0]) | ((unsigned)f2bf(s[1]) << 16);
            pk2.y = (unsigned)f2bf(s[2]) | ((unsigned)f2bf(s[3]) << 16);
            red1[(wv * 14 + i) * 64 + lane] = pk2;
        }
        __syncthreads();
        for (int i = wv; i < 14; i += 8) {
            float s0 = 0.f, s1 = 0.f, s2 = 0.f, s3 = 0.f;
            #pragma unroll
            for (int sw = 0; sw < 8; ++sw) {
                uint2 v = red1[(sw * 14 + i) * 64 + lane];
                s0 += bf2f((unsigned short)(v.x & 0xffffu));
                s1 += bf2f((unsigned short)(v.x >> 16));
                s2 += bf2f((unsigned short)(v.y & 0xffffu));
                s3 += bf2f((unsigned short)(v.y >> 16));
            }
            int m = i >> 1, pt = i & 1;
            float sr[4] = {s0, s1, s2, s3};
            #pragma unroll
            for (int r = 0; r < 4; ++r) {
                int co = m * 16 + q * 4 + r;
                if (co < COFF)
                    pred_lds[co * 32 + pt * 16 + r16] = f2bf(sr[r] + b_off[co]);
            }
        }
        __syncthreads();
    }

    // ===== corner tables (32 p) =====
    uint4* cwi = (uint4*)region;
    uint4* cww = (uint4*)(region + 27648);
    for (int kp = tid; kp < 27 * 32; kp += 512) {
        int k = kp >> 5, p = kp & 31;
        float offz = bf2f(pred_lds[(k * 3 + 0) * 32 + p]);
        float offy = bf2f(pred_lds[(k * 3 + 1) * 32 + p]);
        float offx = bf2f(pred_lds[(k * 3 + 2) * 32 + p]);
        float av   = bf2f(pred_lds[(81 + k) * 32 + p]);
        float alpha = 1.f / (1.f + __expf(-av));
        int kz = k / 9, rem = k - kz * 9, ky = rem / 3, kx = rem - ky * 3;
        float pz = (float)(d + kz - 1) + offz;
        float py = (float)(h + ky - 1) + offy;
        float px = (float)(p + kx - 1) + offx;
        float fz = floorf(pz), fy = floorf(py), fx = floorf(px);
        float tz = pz - fz, ty = py - fy, tx = px - fx;
        int iz0 = (int)fz, iy0 = (int)fy, ix0 = (int)fx;
        unsigned idxs[8]; float wgts[8];
        #pragma unroll
        for (int c8 = 0; c8 < 8; ++c8) {
            int czi = c8 >> 2, cyi = (c8 >> 1) & 1, cxi = c8 & 1;
            int iz = iz0 + czi, iy = iy0 + cyi, ix = ix0 + cxi;
            float wz = czi ? tz : 1.f - tz;
            float wy = cyi ? ty : 1.f - ty;
            float wx = cxi ? tx : 1.f - tx;
            bool ok = ((unsigned)iz < 8u) && ((unsigned)iy < 32u) && ((unsigned)ix < 32u);
            idxs[c8] = ok ? ((unsigned)((iz << 10) + (iy << 5) + ix) << 7) : 0u;
            wgts[c8] = ok ? wz * wy * wx * alpha : 0.f;
        }
        cwi[(k * 2 + 0) * 32 + p] = make_uint4(idxs[0], idxs[1], idxs[2], idxs[3]);
        cwi[(k * 2 + 1) * 32 + p] = make_uint4(idxs[4], idxs[5], idxs[6], idxs[7]);
        cww[k * 32 + p] = make_uint4(
            (unsigned)f2bf(wgts[0]) | ((unsigned)f2bf(wgts[1]) << 16),
            (unsigned)f2bf(wgts[2]) | ((unsigned)f2bf(wgts[3]) << 16),
            (unsigned)f2bf(wgts[4]) | ((unsigned)f2bf(wgts[5]) << 16),
            (unsigned)f2bf(wgts[6]) | ((unsigned)f2bf(wgts[7]) << 16));
    }
    __syncthreads();

    // ===== stage 2: barrier-free sample + in-wave transpose + GEMM =====
    // wave: pt = wv&1 (16-pos tile), ch2 = (wv>>1)&1 (32-ch half), kh = wv>>2
    // lane (sampling): pr = lane>>2 (pos), cg = lane&3 (ch octet)
    const int pt2 = wv & 1, ch2 = (wv >> 1) & 1, kh = wv >> 2;
    const int pr = lane >> 2, cg = lane & 3;
    const int p2 = pt2 * 16 + pr;
    const char* xbB = (const char*)xb + ch2 * 64 + cg * 16;
    const int baddr = (r16 * 4 + q) << 2;     // bpermute source: lane r16*4+q
    f32x4 acc2[4] = {};
    for (int k = kh; k < 27; k += 2) {
        uint4 wq = cww[k * 32 + p2];
        uint4 i0 = cwi[(k * 2 + 0) * 32 + p2];
        uint4 i1 = cwi[(k * 2 + 1) * 32 + p2];
        unsigned iv[8] = {i0.x, i0.y, i0.z, i0.w, i1.x, i1.y, i1.z, i1.w};
        uint4 xv[8];
        #pragma unroll
        for (int c8 = 0; c8 < 8; ++c8)
            xv[c8] = *(const uint4*)(xbB + iv[c8]);
        unsigned wp[4] = {wq.x, wq.y, wq.z, wq.w};
        float sa[8] = {};
        #pragma unroll
        for (int cp = 0; cp < 4; ++cp) {
            unsigned ua[4] = {xv[cp * 2 + 0].x, xv[cp * 2 + 0].y, xv[cp * 2 + 0].z, xv[cp * 2 + 0].w};
            unsigned ub[4] = {xv[cp * 2 + 1].x, xv[cp * 2 + 1].y, xv[cp * 2 + 1].z, xv[cp * 2 + 1].w};
            #pragma unroll
            for (int dw = 0; dw < 4; ++dw) {
                unsigned plo = __builtin_amdgcn_perm(ub[dw], ua[dw], 0x05040100u);
                unsigned phi = __builtin_amdgcn_perm(ub[dw], ua[dw], 0x07060302u);
                sa[dw * 2 + 0] = dot2bf(plo, wp[cp], sa[dw * 2 + 0]);
                sa[dw * 2 + 1] = dot2bf(phi, wp[cp], sa[dw * 2 + 1]);
            }
        }
        // pack to 4 bf16-pair dwords (ch pairs of this lane's octet)
        unsigned pk0 = (unsigned)f2bf(sa[0]) | ((unsigned)f2bf(sa[1]) << 16);
        unsigned pk1 = (unsigned)f2bf(sa[2]) | ((unsigned)f2bf(sa[3]) << 16);
        unsigned pk2 = (unsigned)f2bf(sa[4]) | ((unsigned)f2bf(sa[5]) << 16);
        unsigned pk3 = (unsigned)f2bf(sa[6]) | ((unsigned)f2bf(sa[7]) << 16);
        // in-wave transpose: target lane (q,r16) pulls all 4 dwords from lane r16*4+q
        uint4 bd;
        bd.x = (unsigned)__builtin_amdgcn_ds_bpermute(baddr, (int)pk0);
        bd.y = (unsigned)__builtin_amdgcn_ds_bpermute(baddr, (int)pk1);
        bd.z = (unsigned)__builtin_amdgcn_ds_bpermute(baddr, (int)pk2);
        bd.w = (unsigned)__builtin_amdgcn_ds_bpermute(baddr, (int)pk3);
        bf16x8 bfrag = __builtin_bit_cast(bf16x8, bd);
        const ushort* pwk = pW + (size_t)((k * 2 + ch2) * 4) * 512 + lane * 8;
        #pragma unroll
        for (int m = 0; m < 4; ++m)
            acc2[m] = __builtin_amdgcn_mfma_f32_16x16x32_bf16(
                *(const bf16x8*)(pwk + m * 512), bfrag, acc2[m], 0, 0, 0);
    }

    // ===== epilogue: reduce over (ch2, kh) partials, store =====
    __syncthreads();                 // cwi/cww dead; region -> red2
    f32x4* red2 = (f32x4*)region;
    #pragma unroll
    for (int m = 0; m < 4; ++m)
        red2[(wv * 4 + m) * 64 + lane] = acc2[m];
    __syncthreads();
    {
        const int mo = wv >> 1, pto = wv & 1;   // this wave stores (pt=pto, m=mo)
        f32x4 s = red2[((pto + 0) * 4 + mo) * 64 + lane]
                + red2[((pto + 2) * 4 + mo) * 64 + lane]
                + red2[((pto + 4) * 4 + mo) * 64 + lane]
                + red2[((pto + 6) * 4 + mo) * 64 + lane];
        float* __restrict__ outb = out + (size_t)b * 64 * DHW + spg;
        #pragma unroll
        for (int r = 0; r < 4; ++r) {
            int o = mo * 16 + q * 4 + r;
            outb[(size_t)o * DHW + pto * 16 + r16] = s[r] + b_dcn[o];
        }
    }
}

extern "C" void kernel_launch(void* const* d_in, const int* in_sizes, int n_in,
                              void* d_out, int out_size, void* d_ws, size_t ws_size,
                              hipStream_t stream) {
    const float* x     = (const float*)d_in[0];
    const float* w_off = (const float*)d_in[1];
    const float* b_off = (const float*)d_in[2];
    const float* w_dcn = (const float*)d_in[3];
    const float* b_dcn = (const float*)d_in[4];
    float* out = (float*)d_out;

    ushort* xt  = (ushort*)d_ws;                          // 2,097,152 B
    ushort* pA1 = (ushort*)((char*)d_ws + 2097152);       //   387,072 B
    ushort* pAc = (ushort*)((char*)d_ws + 2484224);       //    21,504 B
    ushort* pW  = (ushort*)((char*)d_ws + 2505728);       //   221,184 B

    k_prep <<<1056, 256, 0, stream>>>(x, w_off, w_dcn, xt, pA1, pAc, pW);
    k_fused<<<512, 512, 0, stream>>>(xt, pA1, pAc, pW, b_off, b_dcn, out);
}